// Round 1
// baseline (378.397 us; speedup 1.0000x reference)
//
#include <hip/hip_runtime.h>

// SchroederReverb: 4 series allpass (N=225,556,441,341, g=0.7) then 4 parallel
// feedback combs (N=1116,1188,1277,1356, g=.84,.82,.80,.78) summed.
//
// Lagged recurrence y[n] = a*y[n-N] + u[n] decouples into N*W chains
// (n = k*N + r, column w). Chain split into S segments resident in ONE block;
// thread (segment s, lane) marches its segment ONCE keeping locals y[0..L)
// in registers, exchanges carries through LDS, then the store pass applies
// the affine correction y_true[j] = y[j] + a^(j+1)*Yin.
//
// Round-7: occupancy/balance rework. AP2-AP4 + combs move to 512-thread
// blocks (S=8, VGPR<=128 via U=4 where needed) -> 2 resident blocks/CU,
// plus an item loop so grid<=512 with balanced (+-1) items. This removes the
// ceil(grid/256) serialized scheduling rounds (AP2 +22, AP4 +85, combs
// +46/82/127/166 block tails) and covers march->sync->store bubbles with the
// second resident block. Granule sizes preserved: V=2 (512B row) for APs,
// V=4 (1KiB chain-pair) for combs. AP1 (grid 225, quantization-free)
// unchanged. NO atomics (round-3: 2.2 TB/s). comb1 write, combs 2-4 RMW.
//
// Semantics (identical to passing rounds 1-6):
//   allpass: y[k=0]=0; y[k] = (x[k] + g*x[k-1]) + (-g)*y[k-1]   per chain
//   comb:    y[k=0]=0; y[k] =  x[k]             +   g *y[k-1]
//
// Buffers: x -> out -> ws -> out -> ws; combs: ws -> out. 64 MiB scratch.

constexpr int W = 128;

template <int V> struct fv { float d[V]; };

template <int V>
__device__ __forceinline__ fv<V> fv_zero() {
  fv<V> r;
#pragma unroll
  for (int c = 0; c < V; ++c) r.d[c] = 0.f;
  return r;
}

// ---- march a block of K steps (state carried through xp, yp) ---------------
template <int MODE, int K, bool PRED, int V>
__device__ __forceinline__
void march_blk(const fv<V>* __restrict__ in, int idx, int stepIdx, int endIdx,
               float g, float a, fv<V>& xp, fv<V>& yp, fv<V>* __restrict__ y) {
  fv<V> xs[K];
#pragma unroll
  for (int u = 0; u < K; ++u) {
    int id = idx + u * stepIdx;
    xs[u] = (!PRED || id < endIdx) ? in[id] : fv_zero<V>();
  }
#pragma unroll
  for (int u = 0; u < K; ++u) {
#pragma unroll
    for (int c = 0; c < V; ++c) {
      float x = xs[u].d[c];
      float uu = (MODE == 0) ? fmaf(g, xp.d[c], x) : x;
      yp.d[c] = fmaf(a, yp.d[c], uu);
    }
    xp = xs[u];
    y[u] = yp;
  }
}

template <int MODE, int CNT, bool PRED, int V, int U = 8>
__device__ __forceinline__
void march_seg(const fv<V>* __restrict__ in, int idx, int stepIdx, int endIdx,
               float g, float a, fv<V>& xp, fv<V>& yp, fv<V>* __restrict__ y) {
  constexpr int NB = CNT / U, R = CNT % U;
#pragma unroll
  for (int b = 0; b < NB; ++b)
    march_blk<MODE, U, PRED, V>(in, idx + b * U * stepIdx, stepIdx, endIdx,
                                g, a, xp, yp, y + b * U);
  if constexpr (R > 0)
    march_blk<MODE, R, PRED, V>(in, idx + NB * U * stepIdx, stepIdx, endIdx,
                                g, a, xp, yp, y + NB * U);
}

// ---- store pass: y_true[j] = y[j] + a^(j+1)*Yin (MODE 2: += out) ----------
template <int MODE, int K, bool PRED, int V>
__device__ __forceinline__
void store_blk(fv<V>* __restrict__ out, int idx, int stepIdx, int endIdx,
               float a, fv<V> Yin, const fv<V>* __restrict__ y, float& p) {
  fv<V> os[K];
  if constexpr (MODE == 2) {
#pragma unroll
    for (int u = 0; u < K; ++u) {
      int id = idx + u * stepIdx;
      os[u] = (!PRED || id < endIdx) ? out[id] : fv_zero<V>();
    }
  }
#pragma unroll
  for (int u = 0; u < K; ++u) {
    int id = idx + u * stepIdx;
    fv<V> v;
#pragma unroll
    for (int c = 0; c < V; ++c) {
      v.d[c] = fmaf(p, Yin.d[c], y[u].d[c]);
      if (MODE == 2) v.d[c] += os[u].d[c];
    }
    if (!PRED || id < endIdx) out[id] = v;
    p *= a;
  }
}

template <int MODE, int CNT, bool PRED, int V, int U = 8>
__device__ __forceinline__
void store_seg(fv<V>* __restrict__ out, int idx, int stepIdx, int endIdx,
               float a, fv<V> Yin, const fv<V>* __restrict__ y, float p0) {
  constexpr int NB = CNT / U, R = CNT % U;
  float p = p0;
#pragma unroll
  for (int b = 0; b < NB; ++b)
    store_blk<MODE, U, PRED, V>(out, idx + b * U * stepIdx, stepIdx, endIdx,
                                a, Yin, y + b * U, p);
  if constexpr (R > 0)
    store_blk<MODE, R, PRED, V>(out, idx + NB * U * stepIdx, stepIdx, endIdx,
                                a, Yin, y + NB * U, p);
}

// ---- one stage, fixed mapping (kept for AP1) -------------------------------
// V<=2: wave = one row (or half-row via blockIdx.y for V=1), grid.x = N.
// V==4: wave = 2 consecutive rows (chains 2bx, 2bx+1), grid.x = ceil(N/2).
template <int MODE, int S, int L, int V, bool ODDN, int U = 8>
__global__ __launch_bounds__(S * 64)
void stage_ro(const fv<V>* __restrict__ in, fv<V>* __restrict__ out,
              int N, float g, float aL, int T) {
  const float a = (MODE == 0) ? -g : g;
  constexpr int RW = W / V;                 // row width in fv<V> units
  __shared__ fv<V> C[S][64];

  const int tid = threadIdx.x;
  const int s   = tid >> 6;                 // segment (wave-uniform)
  const int l6  = tid & 63;

  int r, laneoff;
  bool valid = true;
  if constexpr (V == 4) {
    r = (blockIdx.x << 1) | (l6 >> 5);      // 2 chains per wave
    laneoff = l6 & 31;
    if constexpr (ODDN) valid = (r < N);
  } else {
    r = blockIdx.x;
    laneoff = l6 + blockIdx.y * 64;
  }
  const int stepIdx = N * RW;
  const int endIdx  = valid ? T * RW : 0;
  const int idx0    = (s * L * N + r) * RW + laneoff;

  fv<V> y[L];
  fv<V> xp = fv_zero<V>();
  fv<V> yp = fv_zero<V>();

  if (s == 0) {
    if (MODE == 0) xp = in[r * RW + laneoff];     // x[k=0]; addr safe even if !valid
    y[0] = fv_zero<V>();                          // y[k=0] forced to 0
    march_seg<MODE, L - 1, ODDN, V, U>(in, idx0 + stepIdx, stepIdx, endIdx,
                                       g, a, xp, yp, y + 1);
  } else {
    if (MODE == 0) xp = in[idx0 - stepIdx];       // x[k0-1]; addr safe
    if (!ODDN && s < S - 1)
      march_seg<MODE, L, false, V, U>(in, idx0, stepIdx, endIdx, g, a, xp, yp, y);
    else
      march_seg<MODE, L, true,  V, U>(in, idx0, stepIdx, endIdx, g, a, xp, yp, y);
  }
  C[s][l6] = yp;
  __syncthreads();

  // fold incoming state: Yin = sum_{j<s} aL^(s-1-j) * C[j]
  fv<V> Yin = fv_zero<V>();
  for (int j = 0; j < s; ++j) {
#pragma unroll
    for (int c = 0; c < V; ++c)
      Yin.d[c] = fmaf(aL, Yin.d[c], C[j][l6].d[c]);
  }

  if (!ODDN && s < S - 1)
    store_seg<MODE, L, false, V, U>(out, idx0, stepIdx, endIdx, a, Yin, y, a);
  else
    store_seg<MODE, L, true,  V, U>(out, idx0, stepIdx, endIdx, a, Yin, y, a);
}

// ---- one stage, item-loop mapping (2 resident blocks/CU, balanced) ---------
// Item = one chain (V=2, wave = full 512B row) or chain-pair (V=4, wave = two
// rows, 1KiB granule). Blocks stride the item space: tails <= 1 item. Two
// syncthreads per item: (1) carries visible, (2) LDS C free for next item.
template <int MODE, int S, int L, int V, bool ODDN, int U = 8>
__global__ __launch_bounds__(S * 64, 4)
void stage_loop(const fv<V>* __restrict__ in, fv<V>* __restrict__ out,
                int N, float g, float aL, int T, int items) {
  static_assert(V == 2 || V == 4, "stage_loop supports V=2 or V=4");
  const float a = (MODE == 0) ? -g : g;
  constexpr int RW = W / V;
  __shared__ fv<V> C[S][64];

  const int tid = threadIdx.x;
  const int s   = tid >> 6;
  const int l6  = tid & 63;
  const int stepIdx = N * RW;

  for (int item = blockIdx.x; item < items; item += gridDim.x) {
    int r, laneoff;
    bool valid = true;
    if constexpr (V == 4) {
      r = (item << 1) | (l6 >> 5);          // 2 chains per wave
      laneoff = l6 & 31;
      if constexpr (ODDN) valid = (r < N);
    } else {
      r = item;
      laneoff = l6;
    }
    const int endIdx = valid ? T * RW : 0;
    const int idx0   = (s * L * N + r) * RW + laneoff;

    fv<V> y[L];
    fv<V> xp = fv_zero<V>();
    fv<V> yp = fv_zero<V>();

    if (s == 0) {
      if (MODE == 0) xp = in[r * RW + laneoff];   // x[k=0]; addr safe even if !valid
      y[0] = fv_zero<V>();                        // y[k=0] forced to 0
      march_seg<MODE, L - 1, ODDN, V, U>(in, idx0 + stepIdx, stepIdx, endIdx,
                                         g, a, xp, yp, y + 1);
    } else {
      if (MODE == 0) xp = in[idx0 - stepIdx];     // x[k0-1]; addr safe
      if (!ODDN && s < S - 1)
        march_seg<MODE, L, false, V, U>(in, idx0, stepIdx, endIdx, g, a, xp, yp, y);
      else
        march_seg<MODE, L, true,  V, U>(in, idx0, stepIdx, endIdx, g, a, xp, yp, y);
    }
    C[s][l6] = yp;
    __syncthreads();

    // fold incoming state: Yin = sum_{j<s} aL^(s-1-j) * C[j]
    fv<V> Yin = fv_zero<V>();
    for (int j = 0; j < s; ++j) {
#pragma unroll
      for (int c = 0; c < V; ++c)
        Yin.d[c] = fmaf(aL, Yin.d[c], C[j][l6].d[c]);
    }
    __syncthreads();                        // C reusable by next item

    if (!ODDN && s < S - 1)
      store_seg<MODE, L, false, V, U>(out, idx0, stepIdx, endIdx, a, Yin, y, a);
    else
      store_seg<MODE, L, true,  V, U>(out, idx0, stepIdx, endIdx, a, Yin, y, a);
  }
}

// ---- generic fallback (any T): march-twice float2 kernel -------------------
constexpr int W2 = 64;
template <int MODE, bool STORE>
__device__ __forceinline__
void g_march(const float2* __restrict__ in, float2* __restrict__ out,
             int n, int N, int cnt, int T, int lane, float g, float a,
             float2& xp, float2& yp) {
  for (int j = 0; j < cnt; ++j) {
    float2 x = (n < T) ? in[n * W2 + lane] : make_float2(0.f, 0.f);
    float ux = (MODE == 0) ? fmaf(g, xp.x, x.x) : x.x;
    float uy = (MODE == 0) ? fmaf(g, xp.y, x.y) : x.y;
    yp.x = fmaf(a, yp.x, ux);
    yp.y = fmaf(a, yp.y, uy);
    xp = x;
    if (STORE && n < T) {
      float2 v = yp;
      if (MODE == 2) { v.x += out[n * W2 + lane].x; v.y += out[n * W2 + lane].y; }
      out[n * W2 + lane] = v;
    }
    n += N;
  }
}

template <int MODE>
__global__ __launch_bounds__(1024)
void stage_gen(const float2* __restrict__ in, float2* __restrict__ out,
               int N, float g, float aL, int L, int T) {
  const float a = (MODE == 0) ? -g : g;
  __shared__ float2 C[16][W2];
  const int tid = threadIdx.x, s = tid >> 6, lane = tid & 63;
  const int r = blockIdx.x;
  if (r >= T) return;
  const int n0 = s * L * N + r;
  if (s == 0) {
    float2 xp = make_float2(0.f, 0.f), yp = make_float2(0.f, 0.f);
    if (MODE == 0) xp = in[r * W2 + lane];
    if (MODE != 2) out[r * W2 + lane] = make_float2(0.f, 0.f);
    g_march<MODE, true>(in, out, r + N, N, L - 1, T, lane, g, a, xp, yp);
    C[0][lane] = yp;
    __syncthreads();
    return;
  }
  {
    float2 xp = make_float2(0.f, 0.f), yp = make_float2(0.f, 0.f);
    if (MODE == 0) xp = in[(n0 - N) * W2 + lane];
    g_march<MODE, false>(in, out, n0, N, L, T, lane, g, a, xp, yp);
    C[s][lane] = yp;
  }
  __syncthreads();
  float2 Yin = make_float2(0.f, 0.f);
  for (int j = 0; j < s; ++j) {
    Yin.x = fmaf(aL, Yin.x, C[j][lane].x);
    Yin.y = fmaf(aL, Yin.y, C[j][lane].y);
  }
  float2 xp = make_float2(0.f, 0.f), yp = Yin;
  if (MODE == 0) xp = in[(n0 - N) * W2 + lane];
  g_march<MODE, true>(in, out, n0, N, L, T, lane, g, a, xp, yp);
}

// ---- host ------------------------------------------------------------------
static void pick_SL(int T, int N, int S0, int* Sp, int* Lp) {
  int Kmin = T / N, Kmax = (T + N - 1) / N;
  int S = S0;
  for (; S > 1; --S) {
    int L = (Kmax + S - 1) / S;
    if ((S - 1) * L <= Kmin) break;
  }
  *Sp = S;
  *Lp = (Kmax + *Sp - 1) / *Sp;
}

static float pow_f(float a, int n) {
  double p = 1.0;
  for (int i = 0; i < n; ++i) p *= (double)a;
  return (float)p;
}

extern "C" void kernel_launch(void* const* d_in, const int* in_sizes, int n_in,
                              void* d_out, int out_size, void* d_ws, size_t ws_size,
                              hipStream_t stream) {
  float* out = (float*)d_out;
  float* ws  = (float*)d_ws;              // needs T*W*4 = 64 MiB scratch
  const float* x = (const float*)d_in[0];
  const int T = in_sizes[0] / W;          // 131072

  if (T == 131072) {
    // Coverage: S*L >= Kmax; only-tail-ragged: (S-1)*L <= Kmin.
    const fv<2>* x2  = (const fv<2>*)x;
    fv<2>* o2 = (fv<2>*)out;  const fv<2>* o2c = (const fv<2>*)out;
    fv<2>* w2 = (fv<2>*)ws;   const fv<2>* w2c = (const fv<2>*)ws;
    fv<4>* o4 = (fv<4>*)out;  const fv<4>* o4c = (const fv<4>*)out;
    fv<4>* w4 = (fv<4>*)ws;   const fv<4>* w4c = (const fv<4>*)ws;

    // AP1 N=225 (K=583): V=2, S=16, L=37, grid 225 (<=256: quantization-free)
    hipLaunchKernelGGL((stage_ro<0, 16, 37, 2, false>), dim3(225), dim3(1024),
                       0, stream, x2, o2, 225, 0.7f, pow_f(-0.7f, 37), T);
    // AP2 N=556 (K=236): V=2, S=8, L=30, items=556, grid 512 (2-resident)
    hipLaunchKernelGGL((stage_loop<0, 8, 30, 2, false>), dim3(512), dim3(512),
                       0, stream, o2c, w2, 556, 0.7f, pow_f(-0.7f, 30), T, 556);
    // AP3 N=441 (K=298): V=2, S=8, L=38, items=441, grid 441 (all resident)
    hipLaunchKernelGGL((stage_loop<0, 8, 38, 2, false>), dim3(441), dim3(512),
                       0, stream, w2c, o2, 441, 0.7f, pow_f(-0.7f, 38), T, 441);
    // AP4 N=341 (K=385): V=2, S=8, L=49, U=4 (VGPR cap), items=341, grid 341
    hipLaunchKernelGGL((stage_loop<0, 8, 49, 2, false, 4>), dim3(341), dim3(512),
                       0, stream, o2c, w2, 341, 0.7f, pow_f(-0.7f, 49), T, 341);
    // comb1 N=1116 (K=118): V=4, S=8, L=15, U=4, items=558, grid 512 (write)
    hipLaunchKernelGGL((stage_loop<1, 8, 15, 4, false, 4>), dim3(512), dim3(512),
                       0, stream, w4c, o4, 1116, 0.84f, pow_f(0.84f, 15), T, 558);
    // comb2 N=1188 (K=111): V=4, S=8, L=14, U=4, items=594 (RMW)
    hipLaunchKernelGGL((stage_loop<2, 8, 14, 4, false, 4>), dim3(512), dim3(512),
                       0, stream, w4c, o4, 1188, 0.82f, pow_f(0.82f, 14), T, 594);
    // comb3 N=1277 odd (K=103): V=4, S=8, L=13, U=4, items=639 (RMW, ODDN)
    hipLaunchKernelGGL((stage_loop<2, 8, 13, 4, true, 4>), dim3(512), dim3(512),
                       0, stream, w4c, o4, 1277, 0.80f, pow_f(0.80f, 13), T, 639);
    // comb4 N=1356 (K=97): V=4, S=8, L=13, U=4, items=678 (RMW)
    hipLaunchKernelGGL((stage_loop<2, 8, 13, 4, false, 4>), dim3(512), dim3(512),
                       0, stream, w4c, o4, 1356, 0.78f, pow_f(0.78f, 13), T, 678);
  } else {
    const int   apN[4] = {225, 556, 441, 341};
    const int   cbN[4] = {1116, 1188, 1277, 1356};
    const float cbG[4] = {0.84f, 0.82f, 0.80f, 0.78f};
    const float2* src = (const float2*)x;
    float2* bufs[2] = {(float2*)out, (float2*)ws};
    int cur = 0;
    for (int i = 0; i < 4; ++i) {
      int S, L;
      pick_SL(T, apN[i], 16, &S, &L);
      hipLaunchKernelGGL((stage_gen<0>), dim3(apN[i]), dim3(S * 64), 0, stream,
                         src, bufs[cur], apN[i], 0.7f, pow_f(-0.7f, L), L, T);
      src = bufs[cur];
      cur ^= 1;
    }
    float2* dst = (src == (float2*)out) ? (float2*)ws : (float2*)out;
    for (int i = 0; i < 4; ++i) {
      int S, L;
      pick_SL(T, cbN[i], 16, &S, &L);
      if (i == 0)
        hipLaunchKernelGGL((stage_gen<1>), dim3(cbN[i]), dim3(S * 64), 0, stream,
                           src, dst, cbN[i], cbG[i], pow_f(cbG[i], L), L, T);
      else
        hipLaunchKernelGGL((stage_gen<2>), dim3(cbN[i]), dim3(S * 64), 0, stream,
                           src, dst, cbN[i], cbG[i], pow_f(cbG[i], L), L, T);
    }
    if (dst != (float2*)out)
      hipMemcpyAsync(out, dst, (size_t)T * W * sizeof(float),
                     hipMemcpyDeviceToDevice, stream);
  }
}

// Round 2
// 295.029 us; speedup vs baseline: 1.2826x; 1.2826x over previous
//
#include <hip/hip_runtime.h>

// SchroederReverb: 4 series allpass (N=225,556,441,341, g=0.7) then 4 parallel
// feedback combs (N=1116,1188,1277,1356, g=.84,.82,.80,.78) summed.
//
// Lagged recurrence y[n] = a*y[n-N] + u[n] decouples into N*W chains
// (n = k*N + r, column w). Chain split into S segments resident in ONE block;
// thread (segment s, lane) marches its segment ONCE keeping locals y[0..L)
// in registers, exchanges carries through LDS, then the store pass applies
// the affine correction y_true[j] = y[j] + a^(j+1)*Yin.
//
// Round-8: fix round-7's spill disaster. Empirical: __launch_bounds__(512,4)
// capped VGPR at 64 (CUDA semantics: arg2 = min BLOCKS/CU -> 32 waves/CU ->
// 64 VGPR) -> y[] spilled to scratch (WRITE_SIZE 2.2x, 378us). Now:
//   stage_loop uses __launch_bounds__(512, 2)  -> 16 waves/CU -> cap 128.
//   Natural need: AP2 ~91, AP3 ~107, combs ~91-103 VGPR -> no spills,
//   2 resident 512-thr blocks/CU (covers march->sync->store bubbles, halves
//   grid quantization tails vs round-6).
//   AP4 reverted to round-6 stage_ro (y[49] variant too close to the cap).
//   AP1 round-6 (grid 225 <= 256, quantization-free).
// Granules: V=2 (512B row/wave) for APs, V=4 (1KiB chain-pair) for combs.
// NO atomics (round-3: 2.2 TB/s). comb1 write, combs 2-4 RMW.
//
// Semantics (identical to passing rounds 1-7):
//   allpass: y[k=0]=0; y[k] = (x[k] + g*x[k-1]) + (-g)*y[k-1]   per chain
//   comb:    y[k=0]=0; y[k] =  x[k]             +   g *y[k-1]
//
// Buffers: x -> out -> ws -> out -> ws; combs: ws -> out. 64 MiB scratch.

constexpr int W = 128;

template <int V> struct fv { float d[V]; };

template <int V>
__device__ __forceinline__ fv<V> fv_zero() {
  fv<V> r;
#pragma unroll
  for (int c = 0; c < V; ++c) r.d[c] = 0.f;
  return r;
}

// ---- march a block of K steps (state carried through xp, yp) ---------------
template <int MODE, int K, bool PRED, int V>
__device__ __forceinline__
void march_blk(const fv<V>* __restrict__ in, int idx, int stepIdx, int endIdx,
               float g, float a, fv<V>& xp, fv<V>& yp, fv<V>* __restrict__ y) {
  fv<V> xs[K];
#pragma unroll
  for (int u = 0; u < K; ++u) {
    int id = idx + u * stepIdx;
    xs[u] = (!PRED || id < endIdx) ? in[id] : fv_zero<V>();
  }
#pragma unroll
  for (int u = 0; u < K; ++u) {
#pragma unroll
    for (int c = 0; c < V; ++c) {
      float x = xs[u].d[c];
      float uu = (MODE == 0) ? fmaf(g, xp.d[c], x) : x;
      yp.d[c] = fmaf(a, yp.d[c], uu);
    }
    xp = xs[u];
    y[u] = yp;
  }
}

template <int MODE, int CNT, bool PRED, int V, int U = 8>
__device__ __forceinline__
void march_seg(const fv<V>* __restrict__ in, int idx, int stepIdx, int endIdx,
               float g, float a, fv<V>& xp, fv<V>& yp, fv<V>* __restrict__ y) {
  constexpr int NB = CNT / U, R = CNT % U;
#pragma unroll
  for (int b = 0; b < NB; ++b)
    march_blk<MODE, U, PRED, V>(in, idx + b * U * stepIdx, stepIdx, endIdx,
                                g, a, xp, yp, y + b * U);
  if constexpr (R > 0)
    march_blk<MODE, R, PRED, V>(in, idx + NB * U * stepIdx, stepIdx, endIdx,
                                g, a, xp, yp, y + NB * U);
}

// ---- store pass: y_true[j] = y[j] + a^(j+1)*Yin (MODE 2: += out) ----------
template <int MODE, int K, bool PRED, int V>
__device__ __forceinline__
void store_blk(fv<V>* __restrict__ out, int idx, int stepIdx, int endIdx,
               float a, fv<V> Yin, const fv<V>* __restrict__ y, float& p) {
  fv<V> os[K];
  if constexpr (MODE == 2) {
#pragma unroll
    for (int u = 0; u < K; ++u) {
      int id = idx + u * stepIdx;
      os[u] = (!PRED || id < endIdx) ? out[id] : fv_zero<V>();
    }
  }
#pragma unroll
  for (int u = 0; u < K; ++u) {
    int id = idx + u * stepIdx;
    fv<V> v;
#pragma unroll
    for (int c = 0; c < V; ++c) {
      v.d[c] = fmaf(p, Yin.d[c], y[u].d[c]);
      if (MODE == 2) v.d[c] += os[u].d[c];
    }
    if (!PRED || id < endIdx) out[id] = v;
    p *= a;
  }
}

template <int MODE, int CNT, bool PRED, int V, int U = 8>
__device__ __forceinline__
void store_seg(fv<V>* __restrict__ out, int idx, int stepIdx, int endIdx,
               float a, fv<V> Yin, const fv<V>* __restrict__ y, float p0) {
  constexpr int NB = CNT / U, R = CNT % U;
  float p = p0;
#pragma unroll
  for (int b = 0; b < NB; ++b)
    store_blk<MODE, U, PRED, V>(out, idx + b * U * stepIdx, stepIdx, endIdx,
                                a, Yin, y + b * U, p);
  if constexpr (R > 0)
    store_blk<MODE, R, PRED, V>(out, idx + NB * U * stepIdx, stepIdx, endIdx,
                                a, Yin, y + NB * U, p);
}

// ---- one stage, fixed mapping (AP1, AP4) -----------------------------------
// V<=2: wave = one row (or half-row via blockIdx.y for V=1), grid.x = N.
// V==4: wave = 2 consecutive rows (chains 2bx, 2bx+1), grid.x = ceil(N/2).
template <int MODE, int S, int L, int V, bool ODDN, int U = 8>
__global__ __launch_bounds__(S * 64)
void stage_ro(const fv<V>* __restrict__ in, fv<V>* __restrict__ out,
              int N, float g, float aL, int T) {
  const float a = (MODE == 0) ? -g : g;
  constexpr int RW = W / V;                 // row width in fv<V> units
  __shared__ fv<V> C[S][64];

  const int tid = threadIdx.x;
  const int s   = tid >> 6;                 // segment (wave-uniform)
  const int l6  = tid & 63;

  int r, laneoff;
  bool valid = true;
  if constexpr (V == 4) {
    r = (blockIdx.x << 1) | (l6 >> 5);      // 2 chains per wave
    laneoff = l6 & 31;
    if constexpr (ODDN) valid = (r < N);
  } else {
    r = blockIdx.x;
    laneoff = l6 + blockIdx.y * 64;
  }
  const int stepIdx = N * RW;
  const int endIdx  = valid ? T * RW : 0;
  const int idx0    = (s * L * N + r) * RW + laneoff;

  fv<V> y[L];
  fv<V> xp = fv_zero<V>();
  fv<V> yp = fv_zero<V>();

  if (s == 0) {
    if (MODE == 0) xp = in[r * RW + laneoff];     // x[k=0]; addr safe even if !valid
    y[0] = fv_zero<V>();                          // y[k=0] forced to 0
    march_seg<MODE, L - 1, ODDN, V, U>(in, idx0 + stepIdx, stepIdx, endIdx,
                                       g, a, xp, yp, y + 1);
  } else {
    if (MODE == 0) xp = in[idx0 - stepIdx];       // x[k0-1]; addr safe
    if (!ODDN && s < S - 1)
      march_seg<MODE, L, false, V, U>(in, idx0, stepIdx, endIdx, g, a, xp, yp, y);
    else
      march_seg<MODE, L, true,  V, U>(in, idx0, stepIdx, endIdx, g, a, xp, yp, y);
  }
  C[s][l6] = yp;
  __syncthreads();

  // fold incoming state: Yin = sum_{j<s} aL^(s-1-j) * C[j]
  fv<V> Yin = fv_zero<V>();
  for (int j = 0; j < s; ++j) {
#pragma unroll
    for (int c = 0; c < V; ++c)
      Yin.d[c] = fmaf(aL, Yin.d[c], C[j][l6].d[c]);
  }

  if (!ODDN && s < S - 1)
    store_seg<MODE, L, false, V, U>(out, idx0, stepIdx, endIdx, a, Yin, y, a);
  else
    store_seg<MODE, L, true,  V, U>(out, idx0, stepIdx, endIdx, a, Yin, y, a);
}

// ---- one stage, item-loop mapping (2 resident 512-thr blocks/CU) -----------
// Item = one chain (V=2, wave = full 512B row) or chain-pair (V=4, wave = two
// rows, 1KiB granule). Blocks stride the item space. Two syncthreads per
// item: (1) carries visible, (2) LDS C free for next item.
// __launch_bounds__(512, 2): arg2 = min BLOCKS/CU (CUDA semantics, verified
// round-7: arg2=4 gave VGPR cap 64 = 32 waves/CU). 2 blocks -> 16 waves/CU
// -> VGPR cap 128; all variants need ~91-107 -> no spills.
template <int MODE, int S, int L, int V, bool ODDN, int U = 8>
__global__ __launch_bounds__(S * 64, 2)
void stage_loop(const fv<V>* __restrict__ in, fv<V>* __restrict__ out,
                int N, float g, float aL, int T, int items) {
  static_assert(V == 2 || V == 4, "stage_loop supports V=2 or V=4");
  const float a = (MODE == 0) ? -g : g;
  constexpr int RW = W / V;
  __shared__ fv<V> C[S][64];

  const int tid = threadIdx.x;
  const int s   = tid >> 6;
  const int l6  = tid & 63;
  const int stepIdx = N * RW;

  for (int item = blockIdx.x; item < items; item += gridDim.x) {
    int r, laneoff;
    bool valid = true;
    if constexpr (V == 4) {
      r = (item << 1) | (l6 >> 5);          // 2 chains per wave
      laneoff = l6 & 31;
      if constexpr (ODDN) valid = (r < N);
    } else {
      r = item;
      laneoff = l6;
    }
    const int endIdx = valid ? T * RW : 0;
    const int idx0   = (s * L * N + r) * RW + laneoff;

    fv<V> y[L];
    fv<V> xp = fv_zero<V>();
    fv<V> yp = fv_zero<V>();

    if (s == 0) {
      if (MODE == 0) xp = in[r * RW + laneoff];   // x[k=0]; addr safe even if !valid
      y[0] = fv_zero<V>();                        // y[k=0] forced to 0
      march_seg<MODE, L - 1, ODDN, V, U>(in, idx0 + stepIdx, stepIdx, endIdx,
                                         g, a, xp, yp, y + 1);
    } else {
      if (MODE == 0) xp = in[idx0 - stepIdx];     // x[k0-1]; addr safe
      if (!ODDN && s < S - 1)
        march_seg<MODE, L, false, V, U>(in, idx0, stepIdx, endIdx, g, a, xp, yp, y);
      else
        march_seg<MODE, L, true,  V, U>(in, idx0, stepIdx, endIdx, g, a, xp, yp, y);
    }
    C[s][l6] = yp;
    __syncthreads();

    // fold incoming state: Yin = sum_{j<s} aL^(s-1-j) * C[j]
    fv<V> Yin = fv_zero<V>();
    for (int j = 0; j < s; ++j) {
#pragma unroll
      for (int c = 0; c < V; ++c)
        Yin.d[c] = fmaf(aL, Yin.d[c], C[j][l6].d[c]);
    }
    __syncthreads();                        // C reusable by next item

    if (!ODDN && s < S - 1)
      store_seg<MODE, L, false, V, U>(out, idx0, stepIdx, endIdx, a, Yin, y, a);
    else
      store_seg<MODE, L, true,  V, U>(out, idx0, stepIdx, endIdx, a, Yin, y, a);
  }
}

// ---- generic fallback (any T): march-twice float2 kernel -------------------
constexpr int W2 = 64;
template <int MODE, bool STORE>
__device__ __forceinline__
void g_march(const float2* __restrict__ in, float2* __restrict__ out,
             int n, int N, int cnt, int T, int lane, float g, float a,
             float2& xp, float2& yp) {
  for (int j = 0; j < cnt; ++j) {
    float2 x = (n < T) ? in[n * W2 + lane] : make_float2(0.f, 0.f);
    float ux = (MODE == 0) ? fmaf(g, xp.x, x.x) : x.x;
    float uy = (MODE == 0) ? fmaf(g, xp.y, x.y) : x.y;
    yp.x = fmaf(a, yp.x, ux);
    yp.y = fmaf(a, yp.y, uy);
    xp = x;
    if (STORE && n < T) {
      float2 v = yp;
      if (MODE == 2) { v.x += out[n * W2 + lane].x; v.y += out[n * W2 + lane].y; }
      out[n * W2 + lane] = v;
    }
    n += N;
  }
}

template <int MODE>
__global__ __launch_bounds__(1024)
void stage_gen(const float2* __restrict__ in, float2* __restrict__ out,
               int N, float g, float aL, int L, int T) {
  const float a = (MODE == 0) ? -g : g;
  __shared__ float2 C[16][W2];
  const int tid = threadIdx.x, s = tid >> 6, lane = tid & 63;
  const int r = blockIdx.x;
  if (r >= T) return;
  const int n0 = s * L * N + r;
  if (s == 0) {
    float2 xp = make_float2(0.f, 0.f), yp = make_float2(0.f, 0.f);
    if (MODE == 0) xp = in[r * W2 + lane];
    if (MODE != 2) out[r * W2 + lane] = make_float2(0.f, 0.f);
    g_march<MODE, true>(in, out, r + N, N, L - 1, T, lane, g, a, xp, yp);
    C[0][lane] = yp;
    __syncthreads();
    return;
  }
  {
    float2 xp = make_float2(0.f, 0.f), yp = make_float2(0.f, 0.f);
    if (MODE == 0) xp = in[(n0 - N) * W2 + lane];
    g_march<MODE, false>(in, out, n0, N, L, T, lane, g, a, xp, yp);
    C[s][lane] = yp;
  }
  __syncthreads();
  float2 Yin = make_float2(0.f, 0.f);
  for (int j = 0; j < s; ++j) {
    Yin.x = fmaf(aL, Yin.x, C[j][lane].x);
    Yin.y = fmaf(aL, Yin.y, C[j][lane].y);
  }
  float2 xp = make_float2(0.f, 0.f), yp = Yin;
  if (MODE == 0) xp = in[(n0 - N) * W2 + lane];
  g_march<MODE, true>(in, out, n0, N, T, L, lane, g, a, xp, yp);
}

// ---- host ------------------------------------------------------------------
static void pick_SL(int T, int N, int S0, int* Sp, int* Lp) {
  int Kmin = T / N, Kmax = (T + N - 1) / N;
  int S = S0;
  for (; S > 1; --S) {
    int L = (Kmax + S - 1) / S;
    if ((S - 1) * L <= Kmin) break;
  }
  *Sp = S;
  *Lp = (Kmax + *Sp - 1) / *Sp;
}

static float pow_f(float a, int n) {
  double p = 1.0;
  for (int i = 0; i < n; ++i) p *= (double)a;
  return (float)p;
}

extern "C" void kernel_launch(void* const* d_in, const int* in_sizes, int n_in,
                              void* d_out, int out_size, void* d_ws, size_t ws_size,
                              hipStream_t stream) {
  float* out = (float*)d_out;
  float* ws  = (float*)d_ws;              // needs T*W*4 = 64 MiB scratch
  const float* x = (const float*)d_in[0];
  const int T = in_sizes[0] / W;          // 131072

  if (T == 131072) {
    // Coverage: S*L >= Kmax; only-tail-ragged: (S-1)*L <= Kmin.
    const fv<2>* x2  = (const fv<2>*)x;
    fv<2>* o2 = (fv<2>*)out;  const fv<2>* o2c = (const fv<2>*)out;
    fv<2>* w2 = (fv<2>*)ws;   const fv<2>* w2c = (const fv<2>*)ws;
    fv<4>* o4 = (fv<4>*)out;  const fv<4>* o4c = (const fv<4>*)out;
    fv<4>* w4 = (fv<4>*)ws;   const fv<4>* w4c = (const fv<4>*)ws;

    // AP1 N=225 (K=583): V=2, S=16, L=37, grid 225 (<=256: quantization-free)
    hipLaunchKernelGGL((stage_ro<0, 16, 37, 2, false>), dim3(225), dim3(1024),
                       0, stream, x2, o2, 225, 0.7f, pow_f(-0.7f, 37), T);
    // AP2 N=556 (K=236): V=2, S=8, L=30, items=556, grid 512 (2-resident)
    hipLaunchKernelGGL((stage_loop<0, 8, 30, 2, false>), dim3(512), dim3(512),
                       0, stream, o2c, w2, 556, 0.7f, pow_f(-0.7f, 30), T, 556);
    // AP3 N=441 (K=298): V=2, S=8, L=38, items=441, grid 441 (all resident)
    hipLaunchKernelGGL((stage_loop<0, 8, 38, 2, false>), dim3(441), dim3(512),
                       0, stream, w2c, o2, 441, 0.7f, pow_f(-0.7f, 38), T, 441);
    // AP4 N=341 (K=385): V=2, S=16, L=25, grid 341, 1024 thr (round-6 config;
    // the S=8 variant needs y[49]*2=98+ VGPR, too close to the 128 cap)
    hipLaunchKernelGGL((stage_ro<0, 16, 25, 2, false>), dim3(341), dim3(1024),
                       0, stream, o2c, w2, 341, 0.7f, pow_f(-0.7f, 25), T);
    // comb1 N=1116 (K=118): V=4, S=8, L=15, U=4, items=558, grid 512 (write)
    hipLaunchKernelGGL((stage_loop<1, 8, 15, 4, false, 4>), dim3(512), dim3(512),
                       0, stream, w4c, o4, 1116, 0.84f, pow_f(0.84f, 15), T, 558);
    // comb2 N=1188 (K=111): V=4, S=8, L=14, U=4, items=594 (RMW)
    hipLaunchKernelGGL((stage_loop<2, 8, 14, 4, false, 4>), dim3(512), dim3(512),
                       0, stream, w4c, o4, 1188, 0.82f, pow_f(0.82f, 14), T, 594);
    // comb3 N=1277 odd (K=103): V=4, S=8, L=13, U=4, items=639 (RMW, ODDN)
    hipLaunchKernelGGL((stage_loop<2, 8, 13, 4, true, 4>), dim3(512), dim3(512),
                       0, stream, w4c, o4, 1277, 0.80f, pow_f(0.80f, 13), T, 639);
    // comb4 N=1356 (K=97): V=4, S=8, L=13, U=4, items=678 (RMW)
    hipLaunchKernelGGL((stage_loop<2, 8, 13, 4, false, 4>), dim3(512), dim3(512),
                       0, stream, w4c, o4, 1356, 0.78f, pow_f(0.78f, 13), T, 678);
  } else {
    const int   apN[4] = {225, 556, 441, 341};
    const int   cbN[4] = {1116, 1188, 1277, 1356};
    const float cbG[4] = {0.84f, 0.82f, 0.80f, 0.78f};
    const float2* src = (const float2*)x;
    float2* bufs[2] = {(float2*)out, (float2*)ws};
    int cur = 0;
    for (int i = 0; i < 4; ++i) {
      int S, L;
      pick_SL(T, apN[i], 16, &S, &L);
      hipLaunchKernelGGL((stage_gen<0>), dim3(apN[i]), dim3(S * 64), 0, stream,
                         src, bufs[cur], apN[i], 0.7f, pow_f(-0.7f, L), L, T);
      src = bufs[cur];
      cur ^= 1;
    }
    float2* dst = (src == (float2*)out) ? (float2*)ws : (float2*)out;
    for (int i = 0; i < 4; ++i) {
      int S, L;
      pick_SL(T, cbN[i], 16, &S, &L);
      if (i == 0)
        hipLaunchKernelGGL((stage_gen<1>), dim3(cbN[i]), dim3(S * 64), 0, stream,
                           src, dst, cbN[i], cbG[i], pow_f(cbG[i], L), L, T);
      else
        hipLaunchKernelGGL((stage_gen<2>), dim3(cbN[i]), dim3(S * 64), 0, stream,
                           src, dst, cbN[i], cbG[i], pow_f(cbG[i], L), L, T);
    }
    if (dst != (float2*)out)
      hipMemcpyAsync(out, dst, (size_t)T * W * sizeof(float),
                     hipMemcpyDeviceToDevice, stream);
  }
}

// Round 3
// 277.079 us; speedup vs baseline: 1.3657x; 1.0648x over previous
//
#include <hip/hip_runtime.h>

// SchroederReverb: 4 series allpass (N=225,556,441,341, g=0.7) then 4 parallel
// feedback combs (N=1116,1188,1277,1356, g=.84,.82,.80,.78) summed.
//
// Round-9 insight: the reference "allpass" is y[k] = -g y[k-1] + x[k] + g x[k-1]
// per chain => H(z) = (1+gz^-N)/(1+gz^-N) = IDENTITY, plus a transient from the
// forced y[k=0]=0. With e = y - x: e[k] = -g e[k-1], e[0] = -x[r], so per stage
//     out[n] = x[n] - (-g)^floor(n/N) * x[n mod N].
// Composing 4 stages, the stage-3/4 correction terms vanish identically
// (out2[m]=0 for m<556 and out3[m]=0 for m<441 make their head tables zero):
//     s[n] = x[n] - pw[n/225]*x[n%225] - pw[n/556]*h1[n%556],
// where pw[m] = (-0.7)^m and h1 = out1 head rows [0,556):
//     h1[m<225]=0;  h1[225<=m<450]=x[m]+0.7x[m-225];  h1[m>=450]=x[m]-0.49x[m-450].
// So the 4 AP passes (536 MB HBM) collapse to 2 tiny prep kernels + on-the-fly
// evaluation of s inside the comb kernels (2 extra L2-resident table reads/elem).
// Combs stay genuine IIR scans: proven segmented-scan structure unchanged
// (S=8 waves/block, carries via LDS, affine store fixup, item loop, V=4 =
// 1 KiB/wave granule). comb1 writes out, combs 2-4 RMW. NO atomics (round-3).
// Traffic: 1273 MB -> 737 MB.  __launch_bounds__(512,2): arg2 = min BLOCKS/CU
// (CUDA semantics, verified round-7) -> 16 waves/CU -> VGPR cap 128; march
// unroll U=2 keeps natural use ~100 (round-7 spill lesson).
//
// Comb semantics (identical to passing rounds 1-8):
//   y[k=0]=0; y[k] = g*y[k-1] + s[k]   per chain (k>=1)
//
// ws usage: h1 table 556*128 floats + pw1[1024] + pw2[512]  (~291 KB).

constexpr int W = 128;

template <int V> struct fv { float d[V]; };

template <int V>
__device__ __forceinline__ fv<V> fv_zero() {
  fv<V> r;
#pragma unroll
  for (int c = 0; c < V; ++c) r.d[c] = 0.f;
  return r;
}
using fv2 = fv<2>;
using fv4 = fv<4>;

// ---- fused march: y[k] = a*y[k-1] + s(n),  s computed on the fly ----------
template <int K, bool PRED>
__device__ __forceinline__
void fmarch_blk(const fv4* __restrict__ x, const fv4* __restrict__ h1,
                const float* __restrict__ pw1, const float* __restrict__ pw2,
                int n0, int N, int laneoff, int Tn, float a,
                fv4& yp, fv4* __restrict__ y) {
  constexpr int RW = W / 4;
  fv4 xs[K], t1[K], t2[K];
  float p1[K], p2[K];
#pragma unroll
  for (int u = 0; u < K; ++u) {
    const int n = n0 + u * N;
    const bool ok = !PRED || n < Tn;
    const int q1 = n / 225, r1 = n - q1 * 225;   // compile-time magic-mul divs
    const int q2 = n / 556, r2 = n - q2 * 556;
    xs[u] = ok ? x[n * RW + laneoff] : fv_zero<4>();
    t1[u] = x[r1 * RW + laneoff];                // always in-bounds (mod)
    t2[u] = h1[r2 * RW + laneoff];               // always in-bounds (mod)
    p1[u] = ok ? pw1[q1] : 0.f;                  // p=0 => s=0 for tail/invalid
    p2[u] = ok ? pw2[q2] : 0.f;
  }
#pragma unroll
  for (int u = 0; u < K; ++u) {
#pragma unroll
    for (int c = 0; c < 4; ++c) {
      float s = fmaf(-p1[u], t1[u].d[c], xs[u].d[c]);
      s = fmaf(-p2[u], t2[u].d[c], s);
      yp.d[c] = fmaf(a, yp.d[c], s);
    }
    y[u] = yp;
  }
}

template <int CNT, bool PRED, int U>
__device__ __forceinline__
void fmarch_seg(const fv4* __restrict__ x, const fv4* __restrict__ h1,
                const float* __restrict__ pw1, const float* __restrict__ pw2,
                int n0, int N, int laneoff, int Tn, float a,
                fv4& yp, fv4* __restrict__ y) {
  constexpr int NB = CNT / U, R = CNT % U;
#pragma unroll
  for (int b = 0; b < NB; ++b)
    fmarch_blk<U, PRED>(x, h1, pw1, pw2, n0 + b * U * N, N, laneoff, Tn, a,
                        yp, y + b * U);
  if constexpr (R > 0)
    fmarch_blk<R, PRED>(x, h1, pw1, pw2, n0 + NB * U * N, N, laneoff, Tn, a,
                        yp, y + NB * U);
}

// ---- store pass: y_true[j] = y[j] + a^(j+1)*Yin  (MODE 2: += out) ---------
template <int MODE, int K, bool PRED>
__device__ __forceinline__
void fstore_blk(fv4* __restrict__ out, int n0, int N, int laneoff, int Tn,
                float a, fv4 Yin, const fv4* __restrict__ y, float& p) {
  constexpr int RW = W / 4;
  fv4 os[K];
  if constexpr (MODE == 2) {
#pragma unroll
    for (int u = 0; u < K; ++u) {
      const int n = n0 + u * N;
      os[u] = (!PRED || n < Tn) ? out[n * RW + laneoff] : fv_zero<4>();
    }
  }
#pragma unroll
  for (int u = 0; u < K; ++u) {
    const int n = n0 + u * N;
    fv4 v;
#pragma unroll
    for (int c = 0; c < 4; ++c) {
      v.d[c] = fmaf(p, Yin.d[c], y[u].d[c]);
      if constexpr (MODE == 2) v.d[c] += os[u].d[c];
    }
    if (!PRED || n < Tn) out[n * RW + laneoff] = v;
    p *= a;
  }
}

template <int MODE, int CNT, bool PRED, int U>
__device__ __forceinline__
void fstore_seg(fv4* __restrict__ out, int n0, int N, int laneoff, int Tn,
                float a, fv4 Yin, const fv4* __restrict__ y, float p0) {
  constexpr int NB = CNT / U, R = CNT % U;
  float p = p0;
#pragma unroll
  for (int b = 0; b < NB; ++b)
    fstore_blk<MODE, U, PRED>(out, n0 + b * U * N, N, laneoff, Tn, a, Yin,
                              y + b * U, p);
  if constexpr (R > 0)
    fstore_blk<MODE, R, PRED>(out, n0 + NB * U * N, N, laneoff, Tn, a, Yin,
                              y + NB * U, p);
}

// ---- fused AP+comb stage (item loop, 2 resident 512-thr blocks/CU) ---------
// Item = chain pair (r = 2*item, 2*item+1); wave = 2 rows (1 KiB granule).
// MODE 1: write out.  MODE 2: RMW out.  ODDN: lane-valid guard via Tn=0.
template <int MODE, int S, int L, bool ODDN, int UM, int US>
__global__ __launch_bounds__(S * 64, 2)
void fcomb(const fv4* __restrict__ x, const fv4* __restrict__ h1,
           const float* __restrict__ pw1, const float* __restrict__ pw2,
           fv4* __restrict__ out, int N, float g, float aL, int T, int items) {
  const float a = g;
  __shared__ fv4 C[S][64];
  const int tid = threadIdx.x;
  const int s  = tid >> 6;                  // segment (wave-uniform)
  const int l6 = tid & 63;
  const int laneoff = l6 & 31;

  for (int item = blockIdx.x; item < items; item += gridDim.x) {
    const int r  = (item << 1) | (l6 >> 5); // 2 chains per wave
    const int Tn = (!ODDN || r < N) ? T : 0;
    const int n0 = s * L * N + r;

    fv4 y[L];
    fv4 yp = fv_zero<4>();

    if (s == 0) {
      y[0] = fv_zero<4>();                  // y[k=0] forced to 0
      fmarch_seg<L - 1, ODDN, UM>(x, h1, pw1, pw2, n0 + N, N, laneoff, Tn, a,
                                  yp, y + 1);
    } else if (!ODDN && s < S - 1) {
      fmarch_seg<L, false, UM>(x, h1, pw1, pw2, n0, N, laneoff, Tn, a, yp, y);
    } else {
      fmarch_seg<L, true, UM>(x, h1, pw1, pw2, n0, N, laneoff, Tn, a, yp, y);
    }
    C[s][l6] = yp;
    __syncthreads();

    // fold incoming state: Yin = sum_{j<s} aL^(s-1-j) * C[j]
    fv4 Yin = fv_zero<4>();
    for (int j = 0; j < s; ++j) {
#pragma unroll
      for (int c = 0; c < 4; ++c)
        Yin.d[c] = fmaf(aL, Yin.d[c], C[j][l6].d[c]);
    }
    __syncthreads();                        // C reusable by next item

    if (!ODDN && s < S - 1)
      fstore_seg<MODE, L, false, US>(out, n0, N, laneoff, Tn, a, Yin, y, a);
    else
      fstore_seg<MODE, L, true, US>(out, n0, N, laneoff, Tn, a, Yin, y, a);
  }
}

// ---- prep kernels ----------------------------------------------------------
// pw[m] = (-0.7)^m, computed serially (exact product chain); underflows to 0.
__global__ void prep_pw(float* __restrict__ pw1, float* __restrict__ pw2) {
  if (threadIdx.x == 0) {
    float p = 1.f;
    for (int m = 0; m < 1024; ++m) { pw1[m] = p; p *= -0.7f; }
  } else if (threadIdx.x == 64) {
    float p = 1.f;
    for (int m = 0; m < 512; ++m) { pw2[m] = p; p *= -0.7f; }
  }
}

// h1[m] = allpass-1 output head rows [0,556)
__global__ __launch_bounds__(256)
void prep_h1(const fv2* __restrict__ x, fv2* __restrict__ h1) {
  const int e = blockIdx.x * 256 + threadIdx.x;   // over 556*64 fv2 elems
  if (e >= 556 * 64) return;
  const int n = e >> 6;
  fv2 v;
  if (n < 225) {
    v = fv_zero<2>();
  } else {
    v = x[e];
    const int   d = (n < 450) ? 225 : 450;
    const float c = (n < 450) ? 0.7f : -0.49f;    // -(-0.7)^1 / -(-0.7)^2
    fv2 t = x[e - d * 64];
    v.d[0] = fmaf(c, t.d[0], v.d[0]);
    v.d[1] = fmaf(c, t.d[1], v.d[1]);
  }
  h1[e] = v;
}

// ---- generic fallback (any T): original full recurrence pipeline -----------
constexpr int W2 = 64;
template <int MODE, bool STORE>
__device__ __forceinline__
void g_march(const float2* __restrict__ in, float2* __restrict__ out,
             int n, int N, int cnt, int T, int lane, float g, float a,
             float2& xp, float2& yp) {
  for (int j = 0; j < cnt; ++j) {
    float2 x = (n < T) ? in[n * W2 + lane] : make_float2(0.f, 0.f);
    float ux = (MODE == 0) ? fmaf(g, xp.x, x.x) : x.x;
    float uy = (MODE == 0) ? fmaf(g, xp.y, x.y) : x.y;
    yp.x = fmaf(a, yp.x, ux);
    yp.y = fmaf(a, yp.y, uy);
    xp = x;
    if (STORE && n < T) {
      float2 v = yp;
      if (MODE == 2) { v.x += out[n * W2 + lane].x; v.y += out[n * W2 + lane].y; }
      out[n * W2 + lane] = v;
    }
    n += N;
  }
}

template <int MODE>
__global__ __launch_bounds__(1024)
void stage_gen(const float2* __restrict__ in, float2* __restrict__ out,
               int N, float g, float aL, int L, int T) {
  const float a = (MODE == 0) ? -g : g;
  __shared__ float2 C[16][W2];
  const int tid = threadIdx.x, s = tid >> 6, lane = tid & 63;
  const int r = blockIdx.x;
  if (r >= T) return;
  const int n0 = s * L * N + r;
  if (s == 0) {
    float2 xp = make_float2(0.f, 0.f), yp = make_float2(0.f, 0.f);
    if (MODE == 0) xp = in[r * W2 + lane];
    if (MODE != 2) out[r * W2 + lane] = make_float2(0.f, 0.f);
    g_march<MODE, true>(in, out, r + N, N, L - 1, T, lane, g, a, xp, yp);
    C[0][lane] = yp;
    __syncthreads();
    return;
  }
  {
    float2 xp = make_float2(0.f, 0.f), yp = make_float2(0.f, 0.f);
    if (MODE == 0) xp = in[(n0 - N) * W2 + lane];
    g_march<MODE, false>(in, out, n0, N, L, T, lane, g, a, xp, yp);
    C[s][lane] = yp;
  }
  __syncthreads();
  float2 Yin = make_float2(0.f, 0.f);
  for (int j = 0; j < s; ++j) {
    Yin.x = fmaf(aL, Yin.x, C[j][lane].x);
    Yin.y = fmaf(aL, Yin.y, C[j][lane].y);
  }
  float2 xp = make_float2(0.f, 0.f), yp = Yin;
  if (MODE == 0) xp = in[(n0 - N) * W2 + lane];
  g_march<MODE, true>(in, out, n0, N, L, T, lane, g, a, xp, yp);
}

// ---- host ------------------------------------------------------------------
static void pick_SL(int T, int N, int S0, int* Sp, int* Lp) {
  int Kmin = T / N, Kmax = (T + N - 1) / N;
  int S = S0;
  for (; S > 1; --S) {
    int L = (Kmax + S - 1) / S;
    if ((S - 1) * L <= Kmin) break;
  }
  *Sp = S;
  *Lp = (Kmax + *Sp - 1) / *Sp;
}

static float pow_f(float a, int n) {
  double p = 1.0;
  for (int i = 0; i < n; ++i) p *= (double)a;
  return (float)p;
}

extern "C" void kernel_launch(void* const* d_in, const int* in_sizes, int n_in,
                              void* d_out, int out_size, void* d_ws, size_t ws_size,
                              hipStream_t stream) {
  float* out = (float*)d_out;
  float* ws  = (float*)d_ws;
  const float* x = (const float*)d_in[0];
  const int T = in_sizes[0] / W;          // 131072

  if (T == 131072) {
    float* h1f = ws;                      // 556*128 floats
    float* pw1 = ws + 556 * 128;          // 1024 floats
    float* pw2 = pw1 + 1024;              // 512 floats

    hipLaunchKernelGGL(prep_pw, dim3(1), dim3(128), 0, stream, pw1, pw2);
    hipLaunchKernelGGL(prep_h1, dim3(139), dim3(256), 0, stream,
                       (const fv2*)x, (fv2*)h1f);

    const fv4* x4  = (const fv4*)x;
    const fv4* h14 = (const fv4*)h1f;
    fv4* o4 = (fv4*)out;

    // Coverage per comb: S*L >= Kmax; only-tail-ragged: (S-1)*L <= Kmin.
    // comb1 N=1116 (K=118): S=8, L=15, items=558 (write)
    hipLaunchKernelGGL((fcomb<1, 8, 15, false, 2, 4>), dim3(512), dim3(512),
                       0, stream, x4, h14, pw1, pw2, o4,
                       1116, 0.84f, pow_f(0.84f, 15), T, 558);
    // comb2 N=1188 (K=111): S=8, L=14, items=594 (RMW)
    hipLaunchKernelGGL((fcomb<2, 8, 14, false, 2, 4>), dim3(512), dim3(512),
                       0, stream, x4, h14, pw1, pw2, o4,
                       1188, 0.82f, pow_f(0.82f, 14), T, 594);
    // comb3 N=1277 odd (K=103): S=8, L=13, items=639 (RMW, ODDN)
    hipLaunchKernelGGL((fcomb<2, 8, 13, true, 2, 4>), dim3(512), dim3(512),
                       0, stream, x4, h14, pw1, pw2, o4,
                       1277, 0.80f, pow_f(0.80f, 13), T, 639);
    // comb4 N=1356 (K=97): S=8, L=13, items=678 (RMW)
    hipLaunchKernelGGL((fcomb<2, 8, 13, false, 2, 4>), dim3(512), dim3(512),
                       0, stream, x4, h14, pw1, pw2, o4,
                       1356, 0.78f, pow_f(0.78f, 13), T, 678);
  } else {
    const int   apN[4] = {225, 556, 441, 341};
    const int   cbN[4] = {1116, 1188, 1277, 1356};
    const float cbG[4] = {0.84f, 0.82f, 0.80f, 0.78f};
    const float2* src = (const float2*)x;
    float2* bufs[2] = {(float2*)out, (float2*)ws};
    int cur = 0;
    for (int i = 0; i < 4; ++i) {
      int S, L;
      pick_SL(T, apN[i], 16, &S, &L);
      hipLaunchKernelGGL((stage_gen<0>), dim3(apN[i]), dim3(S * 64), 0, stream,
                         src, bufs[cur], apN[i], 0.7f, pow_f(-0.7f, L), L, T);
      src = bufs[cur];
      cur ^= 1;
    }
    float2* dst = (src == (float2*)out) ? (float2*)ws : (float2*)out;
    for (int i = 0; i < 4; ++i) {
      int S, L;
      pick_SL(T, cbN[i], 16, &S, &L);
      if (i == 0)
        hipLaunchKernelGGL((stage_gen<1>), dim3(cbN[i]), dim3(S * 64), 0, stream,
                           src, dst, cbN[i], cbG[i], pow_f(cbG[i], L), L, T);
      else
        hipLaunchKernelGGL((stage_gen<2>), dim3(cbN[i]), dim3(S * 64), 0, stream,
                           src, dst, cbN[i], cbG[i], pow_f(cbG[i], L), L, T);
    }
    if (dst != (float2*)out)
      hipMemcpyAsync(out, dst, (size_t)T * W * sizeof(float),
                     hipMemcpyDeviceToDevice, stream);
  }
}

// Round 4
// 255.152 us; speedup vs baseline: 1.4830x; 1.0859x over previous
//
#include <hip/hip_runtime.h>

// SchroederReverb: 4 series allpass (N=225,556,441,341, g=0.7) then 4 parallel
// feedback combs (N=1116,1188,1277,1356, g=.84,.82,.80,.78) summed.
//
// Round-9 insight (verified round 3): the "allpass" chain is the identity plus
// a zero-head transient; composing all 4 stages:
//     s[n] = x[n] - pw[n/225]*x[n%225] - pw[n/556]*h1[n%556],
// pw[m] = (-0.7)^m, h1 = 556-row head table of stage-1 output.
//
// Round-10: round-3 counters showed each fused comb at 58us, 2.6 TB/s HBM
// (32%), VALUBusy 6.8% -- not HBM/VALU/occupancy-bound. But aggregate traffic
// (x + two L2 table gathers + out RMW = ~335 MB/kernel) ran at ~5.8 TB/s:
// TOTAL cache-level traffic is the binding resource. So materialize s ONCE
// (prep_s, identical fmaf sequence -> bit-identical values) and make the comb
// marches single-load: aggregate 1273 MB -> 1005 MB, and the march loses the
// magic-div address math + 2/3 of its load registers (U=2 -> 4 deeper load
// pipelining under the 128-VGPR cap).
//
// Layout: s in ws (64 MiB). h1 + pw tables live in the OUT buffer (read only
// by prep_s; comb1 later overwrites every element of out; same-stream order).
// Combs keep the proven segmented-scan structure (S=8 waves, LDS carries,
// affine store fixup, item loop, 2 resident 512-thr blocks/CU;
// __launch_bounds__ arg2 = min BLOCKS/CU, verified round-7).
// comb1 writes out, combs 2-4 RMW. NO atomics (round-3: 2.2 TB/s).
//
// Comb semantics (identical to passing rounds 1-9):
//   y[k=0]=0; y[k] = g*y[k-1] + s[k]   per chain (k>=1)

constexpr int W = 128;

template <int V> struct fv { float d[V]; };

template <int V>
__device__ __forceinline__ fv<V> fv_zero() {
  fv<V> r;
#pragma unroll
  for (int c = 0; c < V; ++c) r.d[c] = 0.f;
  return r;
}
using fv2 = fv<2>;
using fv4 = fv<4>;

// ---- march: y[k] = a*y[k-1] + s[n], s preloaded ---------------------------
template <int K, bool PRED>
__device__ __forceinline__
void fmarch_blk(const fv4* __restrict__ sb, int n0, int N, int laneoff,
                int Tn, float a, fv4& yp, fv4* __restrict__ y) {
  constexpr int RW = W / 4;
  fv4 xs[K];
#pragma unroll
  for (int u = 0; u < K; ++u) {
    const int n = n0 + u * N;
    xs[u] = (!PRED || n < Tn) ? sb[n * RW + laneoff] : fv_zero<4>();
  }
#pragma unroll
  for (int u = 0; u < K; ++u) {
#pragma unroll
    for (int c = 0; c < 4; ++c)
      yp.d[c] = fmaf(a, yp.d[c], xs[u].d[c]);
    y[u] = yp;
  }
}

template <int CNT, bool PRED, int U>
__device__ __forceinline__
void fmarch_seg(const fv4* __restrict__ sb, int n0, int N, int laneoff,
                int Tn, float a, fv4& yp, fv4* __restrict__ y) {
  constexpr int NB = CNT / U, R = CNT % U;
#pragma unroll
  for (int b = 0; b < NB; ++b)
    fmarch_blk<U, PRED>(sb, n0 + b * U * N, N, laneoff, Tn, a, yp, y + b * U);
  if constexpr (R > 0)
    fmarch_blk<R, PRED>(sb, n0 + NB * U * N, N, laneoff, Tn, a, yp, y + NB * U);
}

// ---- store pass: y_true[j] = y[j] + a^(j+1)*Yin  (MODE 2: += out) ---------
template <int MODE, int K, bool PRED>
__device__ __forceinline__
void fstore_blk(fv4* __restrict__ out, int n0, int N, int laneoff, int Tn,
                float a, fv4 Yin, const fv4* __restrict__ y, float& p) {
  constexpr int RW = W / 4;
  fv4 os[K];
  if constexpr (MODE == 2) {
#pragma unroll
    for (int u = 0; u < K; ++u) {
      const int n = n0 + u * N;
      os[u] = (!PRED || n < Tn) ? out[n * RW + laneoff] : fv_zero<4>();
    }
  }
#pragma unroll
  for (int u = 0; u < K; ++u) {
    const int n = n0 + u * N;
    fv4 v;
#pragma unroll
    for (int c = 0; c < 4; ++c) {
      v.d[c] = fmaf(p, Yin.d[c], y[u].d[c]);
      if constexpr (MODE == 2) v.d[c] += os[u].d[c];
    }
    if (!PRED || n < Tn) out[n * RW + laneoff] = v;
    p *= a;
  }
}

template <int MODE, int CNT, bool PRED, int U>
__device__ __forceinline__
void fstore_seg(fv4* __restrict__ out, int n0, int N, int laneoff, int Tn,
                float a, fv4 Yin, const fv4* __restrict__ y, float p0) {
  constexpr int NB = CNT / U, R = CNT % U;
  float p = p0;
#pragma unroll
  for (int b = 0; b < NB; ++b)
    fstore_blk<MODE, U, PRED>(out, n0 + b * U * N, N, laneoff, Tn, a, Yin,
                              y + b * U, p);
  if constexpr (R > 0)
    fstore_blk<MODE, R, PRED>(out, n0 + NB * U * N, N, laneoff, Tn, a, Yin,
                              y + NB * U, p);
}

// ---- comb stage (item loop, 2 resident 512-thr blocks/CU) ------------------
// Item = chain pair (r = 2*item, 2*item+1); wave = 2 rows (1 KiB granule).
// MODE 1: write out.  MODE 2: RMW out.  ODDN: lane-valid guard via Tn=0.
template <int MODE, int S, int L, bool ODDN, int UM, int US>
__global__ __launch_bounds__(S * 64, 2)
void fcomb(const fv4* __restrict__ sb, fv4* __restrict__ out,
           int N, float g, float aL, int T, int items) {
  const float a = g;
  __shared__ fv4 C[S][64];
  const int tid = threadIdx.x;
  const int s  = tid >> 6;                  // segment (wave-uniform)
  const int l6 = tid & 63;
  const int laneoff = l6 & 31;

  for (int item = blockIdx.x; item < items; item += gridDim.x) {
    const int r  = (item << 1) | (l6 >> 5); // 2 chains per wave
    const int Tn = (!ODDN || r < N) ? T : 0;
    const int n0 = s * L * N + r;

    fv4 y[L];
    fv4 yp = fv_zero<4>();

    if (s == 0) {
      y[0] = fv_zero<4>();                  // y[k=0] forced to 0
      fmarch_seg<L - 1, ODDN, UM>(sb, n0 + N, N, laneoff, Tn, a, yp, y + 1);
    } else if (!ODDN && s < S - 1) {
      fmarch_seg<L, false, UM>(sb, n0, N, laneoff, Tn, a, yp, y);
    } else {
      fmarch_seg<L, true, UM>(sb, n0, N, laneoff, Tn, a, yp, y);
    }
    C[s][l6] = yp;
    __syncthreads();

    // fold incoming state: Yin = sum_{j<s} aL^(s-1-j) * C[j]
    fv4 Yin = fv_zero<4>();
    for (int j = 0; j < s; ++j) {
#pragma unroll
      for (int c = 0; c < 4; ++c)
        Yin.d[c] = fmaf(aL, Yin.d[c], C[j][l6].d[c]);
    }
    __syncthreads();                        // C reusable by next item

    if (!ODDN && s < S - 1)
      fstore_seg<MODE, L, false, US>(out, n0, N, laneoff, Tn, a, Yin, y, a);
    else
      fstore_seg<MODE, L, true, US>(out, n0, N, laneoff, Tn, a, Yin, y, a);
  }
}

// ---- prep kernels ----------------------------------------------------------
// pw[m] = (-0.7)^m, serial product chain (underflows to 0 harmlessly).
__global__ void prep_pw(float* __restrict__ pw1, float* __restrict__ pw2) {
  if (threadIdx.x == 0) {
    float p = 1.f;
    for (int m = 0; m < 1024; ++m) { pw1[m] = p; p *= -0.7f; }
  } else if (threadIdx.x == 64) {
    float p = 1.f;
    for (int m = 0; m < 512; ++m) { pw2[m] = p; p *= -0.7f; }
  }
}

// h1[m] = allpass-1 output head rows [0,556)
__global__ __launch_bounds__(256)
void prep_h1(const fv2* __restrict__ x, fv2* __restrict__ h1) {
  const int e = blockIdx.x * 256 + threadIdx.x;   // over 556*64 fv2 elems
  if (e >= 556 * 64) return;
  const int n = e >> 6;
  fv2 v;
  if (n < 225) {
    v = fv_zero<2>();
  } else {
    v = x[e];
    const int   d = (n < 450) ? 225 : 450;
    const float c = (n < 450) ? 0.7f : -0.49f;    // -(-0.7)^1 / -(-0.7)^2
    fv2 t = x[e - d * 64];
    v.d[0] = fmaf(c, t.d[0], v.d[0]);
    v.d[1] = fmaf(c, t.d[1], v.d[1]);
  }
  h1[e] = v;
}

// s[n] = x[n] - pw1[n/225]*x[n%225] - pw2[n/556]*h1[n%556]
// (same fmaf sequence as round-3's in-march evaluation -> bit-identical s)
__global__ __launch_bounds__(1024)
void prep_s(const fv4* __restrict__ x, const fv4* __restrict__ h1,
            const float* __restrict__ pw1, const float* __restrict__ pw2,
            fv4* __restrict__ sb) {
  const int e = blockIdx.x * 1024 + threadIdx.x;  // over T*32 fv4 elems
  const int n  = e >> 5;
  const int lo = e & 31;
  const int q1 = n / 225, r1 = n - q1 * 225;      // compile-time magic-mul
  const int q2 = n / 556, r2 = n - q2 * 556;
  const fv4 xs = x[e];
  const fv4 t1 = x[r1 * 32 + lo];
  const fv4 t2 = h1[r2 * 32 + lo];
  const float p1 = pw1[q1];
  const float p2 = pw2[q2];
  fv4 v;
#pragma unroll
  for (int c = 0; c < 4; ++c) {
    float s = fmaf(-p1, t1.d[c], xs.d[c]);
    v.d[c] = fmaf(-p2, t2.d[c], s);
  }
  sb[e] = v;
}

// ---- generic fallback (any T): original full recurrence pipeline -----------
constexpr int W2 = 64;
template <int MODE, bool STORE>
__device__ __forceinline__
void g_march(const float2* __restrict__ in, float2* __restrict__ out,
             int n, int N, int cnt, int T, int lane, float g, float a,
             float2& xp, float2& yp) {
  for (int j = 0; j < cnt; ++j) {
    float2 x = (n < T) ? in[n * W2 + lane] : make_float2(0.f, 0.f);
    float ux = (MODE == 0) ? fmaf(g, xp.x, x.x) : x.x;
    float uy = (MODE == 0) ? fmaf(g, xp.y, x.y) : x.y;
    yp.x = fmaf(a, yp.x, ux);
    yp.y = fmaf(a, yp.y, uy);
    xp = x;
    if (STORE && n < T) {
      float2 v = yp;
      if (MODE == 2) { v.x += out[n * W2 + lane].x; v.y += out[n * W2 + lane].y; }
      out[n * W2 + lane] = v;
    }
    n += N;
  }
}

template <int MODE>
__global__ __launch_bounds__(1024)
void stage_gen(const float2* __restrict__ in, float2* __restrict__ out,
               int N, float g, float aL, int L, int T) {
  const float a = (MODE == 0) ? -g : g;
  __shared__ float2 C[16][W2];
  const int tid = threadIdx.x, s = tid >> 6, lane = tid & 63;
  const int r = blockIdx.x;
  if (r >= T) return;
  const int n0 = s * L * N + r;
  if (s == 0) {
    float2 xp = make_float2(0.f, 0.f), yp = make_float2(0.f, 0.f);
    if (MODE == 0) xp = in[r * W2 + lane];
    if (MODE != 2) out[r * W2 + lane] = make_float2(0.f, 0.f);
    g_march<MODE, true>(in, out, r + N, N, L - 1, T, lane, g, a, xp, yp);
    C[0][lane] = yp;
    __syncthreads();
    return;
  }
  {
    float2 xp = make_float2(0.f, 0.f), yp = make_float2(0.f, 0.f);
    if (MODE == 0) xp = in[(n0 - N) * W2 + lane];
    g_march<MODE, false>(in, out, n0, N, L, T, lane, g, a, xp, yp);
    C[s][lane] = yp;
  }
  __syncthreads();
  float2 Yin = make_float2(0.f, 0.f);
  for (int j = 0; j < s; ++j) {
    Yin.x = fmaf(aL, Yin.x, C[j][lane].x);
    Yin.y = fmaf(aL, Yin.y, C[j][lane].y);
  }
  float2 xp = make_float2(0.f, 0.f), yp = Yin;
  if (MODE == 0) xp = in[(n0 - N) * W2 + lane];
  g_march<MODE, true>(in, out, n0, N, L, T, lane, g, a, xp, yp);
}

// ---- host ------------------------------------------------------------------
static void pick_SL(int T, int N, int S0, int* Sp, int* Lp) {
  int Kmin = T / N, Kmax = (T + N - 1) / N;
  int S = S0;
  for (; S > 1; --S) {
    int L = (Kmax + S - 1) / S;
    if ((S - 1) * L <= Kmin) break;
  }
  *Sp = S;
  *Lp = (Kmax + *Sp - 1) / *Sp;
}

static float pow_f(float a, int n) {
  double p = 1.0;
  for (int i = 0; i < n; ++i) p *= (double)a;
  return (float)p;
}

extern "C" void kernel_launch(void* const* d_in, const int* in_sizes, int n_in,
                              void* d_out, int out_size, void* d_ws, size_t ws_size,
                              hipStream_t stream) {
  float* out = (float*)d_out;
  float* ws  = (float*)d_ws;
  const float* x = (const float*)d_in[0];
  const int T = in_sizes[0] / W;          // 131072

  if (T == 131072) {
    // Tables live in OUT (read only by prep_s; comb1 overwrites all of out).
    float* h1f = out;                     // 556*128 floats (~278 KB)
    float* pw1 = out + 556 * 128;         // 1024 floats
    float* pw2 = pw1 + 1024;              // 512 floats
    float* sbf = ws;                      // s buffer: T*W floats (64 MiB)

    hipLaunchKernelGGL(prep_pw, dim3(1), dim3(128), 0, stream, pw1, pw2);
    hipLaunchKernelGGL(prep_h1, dim3(139), dim3(256), 0, stream,
                       (const fv2*)x, (fv2*)h1f);
    // T*32 fv4 elems = 4,194,304 = 4096 * 1024 exactly
    hipLaunchKernelGGL(prep_s, dim3(4096), dim3(1024), 0, stream,
                       (const fv4*)x, (const fv4*)h1f, pw1, pw2, (fv4*)sbf);

    const fv4* s4 = (const fv4*)sbf;
    fv4* o4 = (fv4*)out;

    // Coverage per comb: S*L >= Kmax; only-tail-ragged: (S-1)*L <= Kmin.
    // comb1 N=1116 (K=118): S=8, L=15, items=558 (write)
    hipLaunchKernelGGL((fcomb<1, 8, 15, false, 4, 4>), dim3(512), dim3(512),
                       0, stream, s4, o4, 1116, 0.84f, pow_f(0.84f, 15), T, 558);
    // comb2 N=1188 (K=111): S=8, L=14, items=594 (RMW)
    hipLaunchKernelGGL((fcomb<2, 8, 14, false, 4, 4>), dim3(512), dim3(512),
                       0, stream, s4, o4, 1188, 0.82f, pow_f(0.82f, 14), T, 594);
    // comb3 N=1277 odd (K=103): S=8, L=13, items=639 (RMW, ODDN)
    hipLaunchKernelGGL((fcomb<2, 8, 13, true, 4, 4>), dim3(512), dim3(512),
                       0, stream, s4, o4, 1277, 0.80f, pow_f(0.80f, 13), T, 639);
    // comb4 N=1356 (K=97): S=8, L=13, items=678 (RMW)
    hipLaunchKernelGGL((fcomb<2, 8, 13, false, 4, 4>), dim3(512), dim3(512),
                       0, stream, s4, o4, 1356, 0.78f, pow_f(0.78f, 13), T, 678);
  } else {
    const int   apN[4] = {225, 556, 441, 341};
    const int   cbN[4] = {1116, 1188, 1277, 1356};
    const float cbG[4] = {0.84f, 0.82f, 0.80f, 0.78f};
    const float2* src = (const float2*)x;
    float2* bufs[2] = {(float2*)out, (float2*)ws};
    int cur = 0;
    for (int i = 0; i < 4; ++i) {
      int S, L;
      pick_SL(T, apN[i], 16, &S, &L);
      hipLaunchKernelGGL((stage_gen<0>), dim3(apN[i]), dim3(S * 64), 0, stream,
                         src, bufs[cur], apN[i], 0.7f, pow_f(-0.7f, L), L, T);
      src = bufs[cur];
      cur ^= 1;
    }
    float2* dst = (src == (float2*)out) ? (float2*)ws : (float2*)out;
    for (int i = 0; i < 4; ++i) {
      int S, L;
      pick_SL(T, cbN[i], 16, &S, &L);
      if (i == 0)
        hipLaunchKernelGGL((stage_gen<1>), dim3(cbN[i]), dim3(S * 64), 0, stream,
                           src, dst, cbN[i], cbG[i], pow_f(cbG[i], L), L, T);
      else
        hipLaunchKernelGGL((stage_gen<2>), dim3(cbN[i]), dim3(S * 64), 0, stream,
                           src, dst, cbN[i], cbG[i], pow_f(cbG[i], L), L, T);
    }
    if (dst != (float2*)out)
      hipMemcpyAsync(out, dst, (size_t)T * W * sizeof(float),
                     hipMemcpyDeviceToDevice, stream);
  }
}

// Round 5
// 226.986 us; speedup vs baseline: 1.6671x; 1.1241x over previous
//
#include <hip/hip_runtime.h>

// SchroederReverb: 4 series allpass (N=225,556,441,341, g=0.7) then 4 parallel
// feedback combs (N=1116,1188,1277,1356, g=.84,.82,.80,.78) summed.
//
// Round-9 insight (verified rounds 3-4): the "allpass" chain is the identity
// plus a zero-head transient; composing all 4 stages:
//     s[n] = x[n] - pw[n/225]*x[n%225] - pw[n/556]*h1[n%556],
// pw[m] = (-0.7)^m, h1[m] = stage-1 head rows [0,556):
//     h1[m<225]=0; h1[225<=m<450]=x[m]+0.7x[m-225]; h1[m>=450]=x[m]-0.49x[m-450].
//
// Round-11 (this round): two changes on top of round-4's materialized-s design.
//  1. ONE prep kernel: pw computed inline (exp2f(q*log2(0.7)), sign via q&1;
//     error ~1e-4 << 0.0625 tol) and h1 expanded inline from its 2-term x-row
//     formula (gather rows all in first 556 rows of x -> L2-resident).
//     Removes 2 launches + the h1 table write/read + out-buffer aliasing.
//  2. Comb items shrink from chain-PAIRS (V=4, 512 blocks, 1.1-1.3 items/blk
//     -> 46-166 blocks run a 2nd serial item while the rest idle) to SINGLE
//     chains (V=2, wave = one 512B row, still fully coalesced). Items double
//     (1116-1356), per-item VGPR halves (y[L]*2 ~ 30; total ~60) -> 3-4
//     resident 512-thr blocks/CU (launch_bounds arg2 = min BLOCKS/CU, verified
//     round-7; arg2=3 -> cap 85, no spill risk; actual <=64 -> 4 blocks).
//     Tail quantum halves on every comb.
// Combs keep the proven segmented-scan: S=8 waves/block, LDS carries, affine
// store fixup y_true[j] = y[j] + a^(j+1)*Yin, item loop, grid 1024.
// comb1 writes out, combs 2-4 RMW. NO atomics (round-3: 2.2 TB/s).
//
// Comb semantics (identical to passing rounds 1-10):
//   y[k=0]=0; y[k] = g*y[k-1] + s[k]   per chain (k>=1)
//
// Coverage per comb (S=8): S*L >= Kmax, (S-1)*L <= Kmin:
//   comb1 N=1116 K=118/117: L=15 (120>=118, 105<=117)
//   comb2 N=1188 K=111/110: L=14 (112>=111,  98<=110)
//   comb3 N=1277 K=103/102: L=13 (104>=103,  91<=102)
//   comb4 N=1356 K= 97/ 96: L=13 (104>= 97,  91<= 96)

constexpr int W = 128;

template <int V> struct fv { float d[V]; };

template <int V>
__device__ __forceinline__ fv<V> fv_zero() {
  fv<V> r;
#pragma unroll
  for (int c = 0; c < V; ++c) r.d[c] = 0.f;
  return r;
}
using fv2 = fv<2>;
using fv4 = fv<4>;

// ---- march: y[k] = a*y[k-1] + s[n], s preloaded; n is a ROW index ---------
template <int K, bool PRED, int V>
__device__ __forceinline__
void fmarch_blk(const fv<V>* __restrict__ sb, int n0, int N, int laneoff,
                int Tn, float a, fv<V>& yp, fv<V>* __restrict__ y) {
  constexpr int RW = W / V;
  fv<V> xs[K];
#pragma unroll
  for (int u = 0; u < K; ++u) {
    const int n = n0 + u * N;
    xs[u] = (!PRED || n < Tn) ? sb[n * RW + laneoff] : fv_zero<V>();
  }
#pragma unroll
  for (int u = 0; u < K; ++u) {
#pragma unroll
    for (int c = 0; c < V; ++c)
      yp.d[c] = fmaf(a, yp.d[c], xs[u].d[c]);
    y[u] = yp;
  }
}

template <int CNT, bool PRED, int V, int U>
__device__ __forceinline__
void fmarch_seg(const fv<V>* __restrict__ sb, int n0, int N, int laneoff,
                int Tn, float a, fv<V>& yp, fv<V>* __restrict__ y) {
  constexpr int NB = CNT / U, R = CNT % U;
#pragma unroll
  for (int b = 0; b < NB; ++b)
    fmarch_blk<U, PRED, V>(sb, n0 + b * U * N, N, laneoff, Tn, a, yp, y + b * U);
  if constexpr (R > 0)
    fmarch_blk<R, PRED, V>(sb, n0 + NB * U * N, N, laneoff, Tn, a, yp,
                           y + NB * U);
}

// ---- store pass: y_true[j] = y[j] + a^(j+1)*Yin  (MODE 2: += out) ---------
template <int MODE, int K, bool PRED, int V>
__device__ __forceinline__
void fstore_blk(fv<V>* __restrict__ out, int n0, int N, int laneoff, int Tn,
                float a, fv<V> Yin, const fv<V>* __restrict__ y, float& p) {
  constexpr int RW = W / V;
  fv<V> os[K];
  if constexpr (MODE == 2) {
#pragma unroll
    for (int u = 0; u < K; ++u) {
      const int n = n0 + u * N;
      os[u] = (!PRED || n < Tn) ? out[n * RW + laneoff] : fv_zero<V>();
    }
  }
#pragma unroll
  for (int u = 0; u < K; ++u) {
    const int n = n0 + u * N;
    fv<V> v;
#pragma unroll
    for (int c = 0; c < V; ++c) {
      v.d[c] = fmaf(p, Yin.d[c], y[u].d[c]);
      if constexpr (MODE == 2) v.d[c] += os[u].d[c];
    }
    if (!PRED || n < Tn) out[n * RW + laneoff] = v;
    p *= a;
  }
}

template <int MODE, int CNT, bool PRED, int V, int U>
__device__ __forceinline__
void fstore_seg(fv<V>* __restrict__ out, int n0, int N, int laneoff, int Tn,
                float a, fv<V> Yin, const fv<V>* __restrict__ y, float p0) {
  constexpr int NB = CNT / U, R = CNT % U;
  float p = p0;
#pragma unroll
  for (int b = 0; b < NB; ++b)
    fstore_blk<MODE, U, PRED, V>(out, n0 + b * U * N, N, laneoff, Tn, a, Yin,
                                 y + b * U, p);
  if constexpr (R > 0)
    fstore_blk<MODE, R, PRED, V>(out, n0 + NB * U * N, N, laneoff, Tn, a, Yin,
                                 y + NB * U, p);
}

// ---- comb stage: single-chain items, V=2 (wave = one 512B row) -------------
// Item = chain r; items = N. Grid 1024; blocks stride items. Two syncthreads
// per item: (1) carries visible, (2) LDS C free for next item.
// launch_bounds(512,3): min 3 blocks/CU -> VGPR cap 85 (natural ~60; if the
// compiler lands <=64 the hardware fits 4 blocks/CU = 1024 processors).
template <int MODE, int S, int L, int UM, int US>
__global__ __launch_bounds__(S * 64, 3)
void fcomb(const fv2* __restrict__ sb, fv2* __restrict__ out,
           int N, float g, float aL, int T, int items) {
  const float a = g;
  __shared__ fv2 C[S][64];
  const int tid = threadIdx.x;
  const int s  = tid >> 6;                  // segment (wave-uniform)
  const int l6 = tid & 63;                  // lane = fv2 column within row

  for (int item = blockIdx.x; item < items; item += gridDim.x) {
    const int r  = item;
    const int n0 = s * L * N + r;

    fv2 y[L];
    fv2 yp = fv_zero<2>();

    if (s == 0) {
      y[0] = fv_zero<2>();                  // y[k=0] forced to 0
      fmarch_seg<L - 1, false, 2, UM>(sb, n0 + N, N, l6, T, a, yp, y + 1);
    } else if (s < S - 1) {
      fmarch_seg<L, false, 2, UM>(sb, n0, N, l6, T, a, yp, y);
    } else {
      fmarch_seg<L, true, 2, UM>(sb, n0, N, l6, T, a, yp, y);
    }
    C[s][l6] = yp;
    __syncthreads();

    // fold incoming state: Yin = sum_{j<s} aL^(s-1-j) * C[j]
    fv2 Yin = fv_zero<2>();
    for (int j = 0; j < s; ++j) {
#pragma unroll
      for (int c = 0; c < 2; ++c)
        Yin.d[c] = fmaf(aL, Yin.d[c], C[j][l6].d[c]);
    }
    __syncthreads();                        // C reusable by next item

    if (s < S - 1)
      fstore_seg<MODE, L, false, 2, US>(out, n0, N, l6, T, a, Yin, y, a);
    else
      fstore_seg<MODE, L, true, 2, US>(out, n0, N, l6, T, a, Yin, y, a);
  }
}

// ---- single prep kernel: s[n] = x[n] - pw1[q1]*x[r1] - pw2[q2]*h1(r2) ------
// pw inline via exp2f (|err| ~1e-4 rel, tol 0.0625); h1 inline from x rows
// (both gathers hit the first 556 rows of x -> L2-resident).
__global__ __launch_bounds__(1024)
void prep_s(const fv4* __restrict__ x, fv4* __restrict__ sb) {
  const int e = blockIdx.x * 1024 + threadIdx.x;  // over T*32 fv4 elems
  const int n  = e >> 5;
  const int lo = e & 31;
  const int q1 = n / 225, r1 = n - q1 * 225;      // compile-time magic-mul
  const int q2 = n / 556, r2 = n - q2 * 556;
  const float LG = -0.5145731728297583f;          // log2(0.7)
  const float m1 = exp2f((float)q1 * LG);
  const float m2 = exp2f((float)q2 * LG);
  const float p1 = (q1 & 1) ? -m1 : m1;           // (-0.7)^q1
  const float p2 = (q2 & 1) ? -m2 : m2;           // (-0.7)^q2

  const fv4 xs = x[e];
  const fv4 t1 = x[r1 * 32 + lo];
  fv4 t2;
  if (r2 < 225) {
    t2 = fv_zero<4>();
  } else {
    t2 = x[r2 * 32 + lo];
    const int   d = (r2 < 450) ? 225 : 450;
    const float c = (r2 < 450) ? 0.7f : -0.49f;   // -(-0.7)^1 / -(-0.7)^2
    const fv4 tt = x[(r2 - d) * 32 + lo];
#pragma unroll
    for (int k = 0; k < 4; ++k) t2.d[k] = fmaf(c, tt.d[k], t2.d[k]);
  }
  fv4 v;
#pragma unroll
  for (int k = 0; k < 4; ++k) {
    float sv = fmaf(-p1, t1.d[k], xs.d[k]);
    v.d[k] = fmaf(-p2, t2.d[k], sv);
  }
  sb[e] = v;
}

// ---- generic fallback (any T): original full recurrence pipeline -----------
constexpr int W2 = 64;
template <int MODE, bool STORE>
__device__ __forceinline__
void g_march(const float2* __restrict__ in, float2* __restrict__ out,
             int n, int N, int cnt, int T, int lane, float g, float a,
             float2& xp, float2& yp) {
  for (int j = 0; j < cnt; ++j) {
    float2 x = (n < T) ? in[n * W2 + lane] : make_float2(0.f, 0.f);
    float ux = (MODE == 0) ? fmaf(g, xp.x, x.x) : x.x;
    float uy = (MODE == 0) ? fmaf(g, xp.y, x.y) : x.y;
    yp.x = fmaf(a, yp.x, ux);
    yp.y = fmaf(a, yp.y, uy);
    xp = x;
    if (STORE && n < T) {
      float2 v = yp;
      if (MODE == 2) { v.x += out[n * W2 + lane].x; v.y += out[n * W2 + lane].y; }
      out[n * W2 + lane] = v;
    }
    n += N;
  }
}

template <int MODE>
__global__ __launch_bounds__(1024)
void stage_gen(const float2* __restrict__ in, float2* __restrict__ out,
               int N, float g, float aL, int L, int T) {
  const float a = (MODE == 0) ? -g : g;
  __shared__ float2 C[16][W2];
  const int tid = threadIdx.x, s = tid >> 6, lane = tid & 63;
  const int r = blockIdx.x;
  if (r >= T) return;
  const int n0 = s * L * N + r;
  if (s == 0) {
    float2 xp = make_float2(0.f, 0.f), yp = make_float2(0.f, 0.f);
    if (MODE == 0) xp = in[r * W2 + lane];
    if (MODE != 2) out[r * W2 + lane] = make_float2(0.f, 0.f);
    g_march<MODE, true>(in, out, r + N, N, L - 1, T, lane, g, a, xp, yp);
    C[0][lane] = yp;
    __syncthreads();
    return;
  }
  {
    float2 xp = make_float2(0.f, 0.f), yp = make_float2(0.f, 0.f);
    if (MODE == 0) xp = in[(n0 - N) * W2 + lane];
    g_march<MODE, false>(in, out, n0, N, L, T, lane, g, a, xp, yp);
    C[s][lane] = yp;
  }
  __syncthreads();
  float2 Yin = make_float2(0.f, 0.f);
  for (int j = 0; j < s; ++j) {
    Yin.x = fmaf(aL, Yin.x, C[j][lane].x);
    Yin.y = fmaf(aL, Yin.y, C[j][lane].y);
  }
  float2 xp = make_float2(0.f, 0.f), yp = Yin;
  if (MODE == 0) xp = in[(n0 - N) * W2 + lane];
  g_march<MODE, true>(in, out, n0, N, L, T, lane, g, a, xp, yp);
}

// ---- host ------------------------------------------------------------------
static void pick_SL(int T, int N, int S0, int* Sp, int* Lp) {
  int Kmin = T / N, Kmax = (T + N - 1) / N;
  int S = S0;
  for (; S > 1; --S) {
    int L = (Kmax + S - 1) / S;
    if ((S - 1) * L <= Kmin) break;
  }
  *Sp = S;
  *Lp = (Kmax + *Sp - 1) / *Sp;
}

static float pow_f(float a, int n) {
  double p = 1.0;
  for (int i = 0; i < n; ++i) p *= (double)a;
  return (float)p;
}

extern "C" void kernel_launch(void* const* d_in, const int* in_sizes, int n_in,
                              void* d_out, int out_size, void* d_ws, size_t ws_size,
                              hipStream_t stream) {
  float* out = (float*)d_out;
  float* ws  = (float*)d_ws;
  const float* x = (const float*)d_in[0];
  const int T = in_sizes[0] / W;          // 131072

  if (T == 131072) {
    float* sbf = ws;                      // s buffer: T*W floats (64 MiB)

    // T*32 fv4 elems = 4,194,304 = 4096 * 1024 exactly
    hipLaunchKernelGGL(prep_s, dim3(4096), dim3(1024), 0, stream,
                       (const fv4*)x, (fv4*)sbf);

    const fv2* s2 = (const fv2*)sbf;
    fv2* o2 = (fv2*)out;

    // Single-chain items (items = N), grid 1024, S=8 waves.
    // comb1 N=1116 (K=118): L=15 (write)
    hipLaunchKernelGGL((fcomb<1, 8, 15, 4, 4>), dim3(1024), dim3(512),
                       0, stream, s2, o2, 1116, 0.84f, pow_f(0.84f, 15), T, 1116);
    // comb2 N=1188 (K=111): L=14 (RMW)
    hipLaunchKernelGGL((fcomb<2, 8, 14, 4, 4>), dim3(1024), dim3(512),
                       0, stream, s2, o2, 1188, 0.82f, pow_f(0.82f, 14), T, 1188);
    // comb3 N=1277 (K=103): L=13 (RMW)
    hipLaunchKernelGGL((fcomb<2, 8, 13, 4, 4>), dim3(1024), dim3(512),
                       0, stream, s2, o2, 1277, 0.80f, pow_f(0.80f, 13), T, 1277);
    // comb4 N=1356 (K=97): L=13 (RMW)
    hipLaunchKernelGGL((fcomb<2, 8, 13, 4, 4>), dim3(1024), dim3(512),
                       0, stream, s2, o2, 1356, 0.78f, pow_f(0.78f, 13), T, 1356);
  } else {
    const int   apN[4] = {225, 556, 441, 341};
    const int   cbN[4] = {1116, 1188, 1277, 1356};
    const float cbG[4] = {0.84f, 0.82f, 0.80f, 0.78f};
    const float2* src = (const float2*)x;
    float2* bufs[2] = {(float2*)out, (float2*)ws};
    int cur = 0;
    for (int i = 0; i < 4; ++i) {
      int S, L;
      pick_SL(T, apN[i], 16, &S, &L);
      hipLaunchKernelGGL((stage_gen<0>), dim3(apN[i]), dim3(S * 64), 0, stream,
                         src, bufs[cur], apN[i], 0.7f, pow_f(-0.7f, L), L, T);
      src = bufs[cur];
      cur ^= 1;
    }
    float2* dst = (src == (float2*)out) ? (float2*)ws : (float2*)out;
    for (int i = 0; i < 4; ++i) {
      int S, L;
      pick_SL(T, cbN[i], 16, &S, &L);
      if (i == 0)
        hipLaunchKernelGGL((stage_gen<1>), dim3(cbN[i]), dim3(S * 64), 0, stream,
                           src, dst, cbN[i], cbG[i], pow_f(cbG[i], L), L, T);
      else
        hipLaunchKernelGGL((stage_gen<2>), dim3(cbN[i]), dim3(S * 64), 0, stream,
                           src, dst, cbN[i], cbG[i], pow_f(cbG[i], L), L, T);
    }
    if (dst != (float2*)out)
      hipMemcpyAsync(out, dst, (size_t)T * W * sizeof(float),
                     hipMemcpyDeviceToDevice, stream);
  }
}